// Round 22
// baseline (3269.153 us; speedup 1.0000x reference)
//
#include <hip/hip_runtime.h>

#define BB 8
#define TT 16
#define HH 256
#define WW 256
#define HW (HH*WW)            // 65536
#define NPT (BB*HW)           // 524288 points
#define EMPTY_FLOOR 0.012f

// ws (20 MB, proven): st float4[NPT]=8MB | rec Rec[NPT]=6MB | hist u32[NPT]=2MB
//                     | off u32[NPT]=2MB | meta u32[NPT]=2MB
// Arithmetic VERBATIM R15 (A-init f32 bits; f64 step math, f32 state rounding;
// R6-f32 defused splat weights; empty-cell floor 0.012). DO NOT TOUCH.
// R22: atomic-free scatter via hist-rank meta; decoupled rowbase scan in
// k_scan (last-block-done); init+adv(0) fused; hist zeroed by memsetAsync.

struct Rec { float sx, sy, nR; };

__device__ unsigned g_rowtot[BB][HH];        // per-row record counts
__device__ unsigned g_rowbase[BB][HH + 1];   // exclusive row bases + total
__device__ unsigned g_cnt[BB];               // zero-init; self-resetting

__device__ __forceinline__ float fmul_sr(float a, float b) {
    float r = a * b;
    __asm__("" : "+v"(r));
    return r;
}

// ---- R15-verbatim advection core; histograms bin and records rank ----
__device__ __forceinline__ void adv_core(const float* __restrict__ dec,
                                         float4& s,
                                         unsigned* __restrict__ hist,
                                         unsigned* __restrict__ meta,
                                         int idx, int b, int t) {
    const float* U = dec + (size_t)((b * TT + t) * 3) * HW;
    const float* V = U + HW;
    const float* C = U + 2 * HW;

    double X = (double)s.x, Y = (double)s.y, R = (double)s.z;
    double ix = X * 256.0 - 0.5;
    double iy = Y * 256.0 - 0.5;
    double x0 = floor(ix);
    double y0 = floor(iy);

    double gU = 0.0, gV = 0.0, gC = 0.0;
    #pragma unroll
    for (int k = 0; k < 4; ++k) {
        double dxf = (double)(k & 1), dyf = (double)(k >> 1);
        double xc = x0 + dxf, yc = y0 + dyf;
        double w = (1.0 - fabs(ix - xc)) * (1.0 - fabs(iy - yc));
        bool valid = (xc >= 0.0) && (xc < 256.0) && (yc >= 0.0) && (yc < 256.0);
        double wv = valid ? w : 0.0;
        int xi = (int)fmin(fmax(xc, 0.0), 255.0);
        int yi = (int)fmin(fmax(yc, 0.0), 255.0);
        int ii = yi * WW + xi;
        double uT = (((double)U[ii] - 0.5) * 5.0) / 256.0;
        double vT = (((double)V[ii] - 0.5) * 5.0) / 256.0;
        double cT = (double)C[ii];
        gU = gU + uT * wv;
        gV = gV + vT * wv;
        gC = gC + cT * wv;
    }

    double nXd = X + gU; nXd = fmin(fmax(nXd, 0.0), 1.0);
    double nYd = Y + gV; nYd = fmin(fmax(nYd, 0.0), 1.0);
    double nRd = R * gC; nRd = fmin(fmax(nRd, 0.0), 1.0);
    float nX = (float)nXd;
    float nY = (float)nYd;
    float nR = (float)nRd;
    s.x = nX; s.y = nY; s.z = nR;

    float sx = fmul_sr(nX, 255.0f);
    float sy = fmul_sr(nY, 255.0f);
    int bin = ((int)floorf(sy)) * 256 + (int)floorf(sx);   // 0..65535
    unsigned rank = atomicAdd(&hist[(b << 16) + bin], 1u); // rank <= 65535
    meta[idx] = ((unsigned)bin << 16) | rank;
}

// init state + advection of step 0 (hist pre-zeroed by memsetAsync)
__global__ __launch_bounds__(256) void k_initadv(
        const float* __restrict__ x, const float* __restrict__ dec,
        float4* __restrict__ st, unsigned* __restrict__ hist,
        unsigned* __restrict__ meta) {
#pragma clang fp contract(off)
    int b   = blockIdx.x & 7;
    int sub = blockIdx.x >> 3;
    int p0  = (b << 16) + sub * 512 + threadIdx.x;
    #pragma unroll
    for (int q = 0; q < 2; ++q) {
        int idx = p0 + q * 256;
        int p  = idx & (HW - 1);
        int px = p & (WW - 1);
        int py = p >> 8;
        float4 s;
        s.x = (float)px * (1.0f / 255.0f);   // A-init bits (proven basin)
        s.y = (float)py * (1.0f / 255.0f);
        s.z = x[(size_t)(b * TT + (TT - 1)) * HW + p];
        s.w = 0.0f;
        adv_core(dec, s, hist, meta, idx, b, 0);
        st[idx] = s;
    }
}

// 2048 blocks (batch = blockIdx&7, row = blockIdx>>3): row-local exclusive
// scan -> off; rezero hist; rowtot; last block per batch scans rowbases.
__global__ __launch_bounds__(256) void k_scan(unsigned* __restrict__ hist,
                                              unsigned* __restrict__ off) {
    int b   = blockIdx.x & 7;
    int row = blockIdx.x >> 3;
    int tid = threadIdx.x;
    int bin = (b << 16) + row * 256 + tid;

    unsigned v = hist[bin];
    __shared__ unsigned ls[256];
    __shared__ unsigned flag;
    ls[tid] = v;
    __syncthreads();
    #pragma unroll
    for (int ofs = 1; ofs < 256; ofs <<= 1) {
        unsigned u = (tid >= ofs) ? ls[tid - ofs] : 0u;
        __syncthreads();
        ls[tid] += u;
        __syncthreads();
    }
    off[bin]  = ls[tid] - v;
    hist[bin] = 0u;
    if (tid == 255) g_rowtot[b][row] = ls[255];

    __threadfence();                       // release my writes
    __syncthreads();
    if (tid == 0) {
        unsigned prev = atomicAdd(&g_cnt[b], 1u);
        flag = (prev == 255) ? 1u : 0u;
    }
    __syncthreads();
    if (flag) {                            // last block of this batch
        __threadfence();                   // acquire all rowtots
        unsigned rv = __hip_atomic_load(&g_rowtot[b][tid],
                                        __ATOMIC_RELAXED,
                                        __HIP_MEMORY_SCOPE_AGENT);
        ls[tid] = rv;
        __syncthreads();
        #pragma unroll
        for (int ofs = 1; ofs < 256; ofs <<= 1) {
            unsigned u = (tid >= ofs) ? ls[tid - ofs] : 0u;
            __syncthreads();
            ls[tid] += u;
            __syncthreads();
        }
        g_rowbase[b][tid] = ls[tid] - rv;
        if (tid == 255) { g_rowbase[b][256] = ls[255]; g_cnt[b] = 0u; }
    }
}

// atomic-free scatter: slot = rowbase[row] + off[bin] + rank
__global__ __launch_bounds__(256) void k_scat(const float4* __restrict__ st,
                                              const unsigned* __restrict__ meta,
                                              const unsigned* __restrict__ off,
                                              Rec* __restrict__ rec) {
#pragma clang fp contract(off)
    int b   = blockIdx.x & 7;
    int sub = blockIdx.x >> 3;
    int p0  = (b << 16) + sub * 512 + threadIdx.x;
    #pragma unroll
    for (int q = 0; q < 2; ++q) {
        int idx = p0 + q * 256;
        float4 s = st[idx];
        unsigned m = meta[idx];
        unsigned bin = m >> 16, rank = m & 0xFFFFu;
        unsigned row = bin >> 8;
        unsigned slot = g_rowbase[b][row] + off[(b << 16) + bin] + rank;
        Rec r;
        r.sx = fmul_sr(s.x, 255.0f);   // same bits as adv_core's sx
        r.sy = fmul_sr(s.y, 255.0f);
        r.nR = s.z;
        rec[((size_t)b << 16) + slot] = r;
    }
}

// per-tile gather (32x16 cells) + fused advection of step t+1
__global__ __launch_bounds__(256) void k_gathadv(
        const Rec* __restrict__ rec, const unsigned* __restrict__ off,
        float* __restrict__ out, const float* __restrict__ dec,
        float4* __restrict__ st, unsigned* __restrict__ hist,
        unsigned* __restrict__ meta, int t) {
#pragma clang fp contract(off)
    __shared__ float a_lds[16][32];
    __shared__ float w_lds[16][32];

    int b    = blockIdx.x & 7;
    int tile = blockIdx.x >> 3;          // 0..127
    int x0 = (tile & 7) * 32;
    int y0 = (tile >> 3) * 16;
    int tid = threadIdx.x;

    a_lds[tid >> 5][tid & 31] = 0.0f;
    w_lds[tid >> 5][tid & 31] = 0.0f;
    a_lds[(tid >> 5) + 8][tid & 31] = 0.0f;
    w_lds[(tid >> 5) + 8][tid & 31] = 0.0f;
    __syncthreads();

    const unsigned* ob = off + (b << 16);
    const Rec*      rb = rec + ((size_t)b << 16);
    const unsigned* rbase = g_rowbase[b];
    int wave = tid >> 6, lane = tid & 63;

    for (int r = wave; r < 17; r += 4) {
        int by = y0 - 1 + r;
        if (by < 0) continue;            // by <= 255 always
        int bx0 = (x0 == 0) ? 0 : x0 - 1;
        int bx1 = x0 + 31;               // <= 255
        unsigned base = rbase[by];
        unsigned sbeg = base + ob[by * 256 + bx0];
        unsigned send = (bx1 == 255) ? rbase[by + 1]
                                     : base + ob[by * 256 + bx1 + 1];
        for (unsigned i = sbeg + lane; i < send; i += 64) {
            Rec rr = rb[i];
            float sx0f = floorf(rr.sx), sy0f = floorf(rr.sy);
            #pragma unroll
            for (int k = 0; k < 4; ++k) {
                float dxf = (float)(k & 1), dyf = (float)(k >> 1);
                float xc = sx0f + dxf, yc = sy0f + dyf;   // exact
                int cxi = (int)xc, cy = (int)yc;
                if (cxi >= x0 && cxi < x0 + 32 && cy >= y0 && cy < y0 + 16) {
                    float w = fmul_sr(1.0f - fabsf(rr.sx - xc),
                                      1.0f - fabsf(rr.sy - yc));
                    if (w != 0.0f) {                      // matches splat skip
                        atomicAdd(&a_lds[cy - y0][cxi - x0], fmul_sr(rr.nR, w));
                        atomicAdd(&w_lds[cy - y0][cxi - x0], w);
                    }
                }
            }
        }
    }
    __syncthreads();

    size_t obase = (size_t)(b * TT + t) * HW;
    #pragma unroll
    for (int q = 0; q < 2; ++q) {
        int c = tid + q * 256;
        int row = c >> 5, col = c & 31;
        float a = a_lds[row][col];
        float w = w_lds[row][col];
        out[obase + (size_t)(y0 + row) * 256 + x0 + col] =
            (w == 0.0f) ? EMPTY_FLOOR : a / fmaxf(w, 1e-8f);
    }

    // ---- fused advection of step t+1 ----
    int tA = t + 1;
    if (tA < TT) {
        int sub = blockIdx.x >> 3;
        int p0  = (b << 16) + sub * 512 + tid;
        #pragma unroll
        for (int q = 0; q < 2; ++q) {
            int idx = p0 + q * 256;
            float4 s = st[idx];
            adv_core(dec, s, hist, meta, idx, b, tA);
            st[idx] = s;
        }
    }
}

extern "C" void kernel_launch(void* const* d_in, const int* in_sizes, int n_in,
                              void* d_out, int out_size, void* d_ws, size_t ws_size,
                              hipStream_t stream) {
    const float* x   = (const float*)d_in[0];
    const float* dec = (const float*)d_in[1];
    float* out = (float*)d_out;

    float4*   st   = (float4*)d_ws;                                       // 8 MB
    Rec*      rec  = (Rec*)(st + (size_t)NPT);                            // 6 MB
    unsigned* hist = (unsigned*)((char*)rec + (size_t)NPT * sizeof(Rec)); // 2 MB
    unsigned* off  = hist + (size_t)NPT;                                  // 2 MB
    unsigned* meta = off + (size_t)NPT;                                   // 2 MB = 20 MB

    hipMemsetAsync(hist, 0, (size_t)NPT * sizeof(unsigned), stream);
    k_initadv<<<1024, 256, 0, stream>>>(x, dec, st, hist, meta);
    for (int t = 0; t < TT; ++t) {
        k_scan<<<2048, 256, 0, stream>>>(hist, off);
        k_scat<<<1024, 256, 0, stream>>>(st, meta, off, rec);
        k_gathadv<<<1024, 256, 0, stream>>>(rec, off, out, dec, st, hist, meta, t);
    }
}

// Round 23
// 710.615 us; speedup vs baseline: 4.6005x; 4.6005x over previous
//
#include <hip/hip_runtime.h>

#define BB 8
#define TT 16
#define HH 256
#define WW 256
#define HW (HH*WW)            // 65536
#define NPT (BB*HW)           // 524288 points
#define EMPTY_FLOOR 0.012f

// ws (18 MB): st float4[NPT]=8MB | rec Rec[NPT]=6MB | hist u32[NPT]=2MB |
//             off u32[NPT]=2MB | meta u32[NPT]=2MB  -> 20 MB (proven).
// Arithmetic VERBATIM R15 (A-init f32 bits; f64 step math, f32 state rounding;
// R6-f32 defused splat weights; empty-cell floor 0.012). DO NOT TOUCH.
// R23 = R21 structure (fence-free two-level scan; consumers LDS-scan g_rowtot)
//     + R22's good parts (atomic-free scatter via meta rank; fused init+adv;
//       memsetAsync hist). NO __threadfence anywhere (R22's 2.3ms poison).

struct Rec { float sx, sy, nR; };

__device__ unsigned g_rowtot[BB][HH];   // 8 KB; visibility via kernel boundary

__device__ __forceinline__ float fmul_sr(float a, float b) {
    float r = a * b;
    __asm__("" : "+v"(r));
    return r;
}

// ---- R15-verbatim advection core; histograms bin and records rank ----
__device__ __forceinline__ void adv_core(const float* __restrict__ dec,
                                         float4& s,
                                         unsigned* __restrict__ hist,
                                         unsigned* __restrict__ meta,
                                         int idx, int b, int t) {
    const float* U = dec + (size_t)((b * TT + t) * 3) * HW;
    const float* V = U + HW;
    const float* C = U + 2 * HW;

    double X = (double)s.x, Y = (double)s.y, R = (double)s.z;
    double ix = X * 256.0 - 0.5;
    double iy = Y * 256.0 - 0.5;
    double x0 = floor(ix);
    double y0 = floor(iy);

    double gU = 0.0, gV = 0.0, gC = 0.0;
    #pragma unroll
    for (int k = 0; k < 4; ++k) {
        double dxf = (double)(k & 1), dyf = (double)(k >> 1);
        double xc = x0 + dxf, yc = y0 + dyf;
        double w = (1.0 - fabs(ix - xc)) * (1.0 - fabs(iy - yc));
        bool valid = (xc >= 0.0) && (xc < 256.0) && (yc >= 0.0) && (yc < 256.0);
        double wv = valid ? w : 0.0;
        int xi = (int)fmin(fmax(xc, 0.0), 255.0);
        int yi = (int)fmin(fmax(yc, 0.0), 255.0);
        int ii = yi * WW + xi;
        double uT = (((double)U[ii] - 0.5) * 5.0) / 256.0;
        double vT = (((double)V[ii] - 0.5) * 5.0) / 256.0;
        double cT = (double)C[ii];
        gU = gU + uT * wv;
        gV = gV + vT * wv;
        gC = gC + cT * wv;
    }

    double nXd = X + gU; nXd = fmin(fmax(nXd, 0.0), 1.0);
    double nYd = Y + gV; nYd = fmin(fmax(nYd, 0.0), 1.0);
    double nRd = R * gC; nRd = fmin(fmax(nRd, 0.0), 1.0);
    float nX = (float)nXd;
    float nY = (float)nYd;
    float nR = (float)nRd;
    s.x = nX; s.y = nY; s.z = nR;

    float sx = fmul_sr(nX, 255.0f);
    float sy = fmul_sr(nY, 255.0f);
    int bin = ((int)floorf(sy)) * 256 + (int)floorf(sx);   // 0..65535
    unsigned rank = atomicAdd(&hist[(b << 16) + bin], 1u); // rank < 65536
    meta[idx] = ((unsigned)bin << 16) | rank;
}

// init state + advection of step 0 (hist pre-zeroed by memsetAsync)
__global__ __launch_bounds__(256) void k_initadv(
        const float* __restrict__ x, const float* __restrict__ dec,
        float4* __restrict__ st, unsigned* __restrict__ hist,
        unsigned* __restrict__ meta) {
#pragma clang fp contract(off)
    int b   = blockIdx.x & 7;
    int sub = blockIdx.x >> 3;
    int p0  = (b << 16) + sub * 512 + threadIdx.x;
    #pragma unroll
    for (int q = 0; q < 2; ++q) {
        int idx = p0 + q * 256;
        int p  = idx & (HW - 1);
        int px = p & (WW - 1);
        int py = p >> 8;
        float4 s;
        s.x = (float)px * (1.0f / 255.0f);   // A-init bits (proven basin)
        s.y = (float)py * (1.0f / 255.0f);
        s.z = x[(size_t)(b * TT + (TT - 1)) * HW + p];
        s.w = 0.0f;
        adv_core(dec, s, hist, meta, idx, b, 0);
        st[idx] = s;
    }
}

// 2048 blocks (batch=blockIdx&7, row=blockIdx>>3): row-local exclusive scan.
// Fence-free (R21-proven): consumers see off/hist/g_rowtot via kernel boundary.
__global__ __launch_bounds__(256) void k_scan(unsigned* __restrict__ hist,
                                              unsigned* __restrict__ off) {
    int b   = blockIdx.x & 7;
    int row = blockIdx.x >> 3;
    int tid = threadIdx.x;
    int bin = (b << 16) + row * 256 + tid;

    unsigned v = hist[bin];
    __shared__ unsigned ls[256];
    ls[tid] = v;
    __syncthreads();
    #pragma unroll
    for (int ofs = 1; ofs < 256; ofs <<= 1) {
        unsigned u = (tid >= ofs) ? ls[tid - ofs] : 0u;
        __syncthreads();
        ls[tid] += u;
        __syncthreads();
    }
    off[bin]  = ls[tid] - v;
    hist[bin] = 0u;
    if (tid == 255) g_rowtot[b][row] = ls[255];
}

// LDS helper: exclusive row-base scan of g_rowtot[b][*] (R21-proven cheap).
__device__ __forceinline__ void load_rowbases(int b, unsigned* rbase,
                                              unsigned* rtot) {
    int tid = threadIdx.x;
    unsigned v = g_rowtot[b][tid];
    rtot[tid]  = v;
    rbase[tid] = v;
    __syncthreads();
    #pragma unroll
    for (int ofs = 1; ofs < 256; ofs <<= 1) {
        unsigned u = (tid >= ofs) ? rbase[tid - ofs] : 0u;
        __syncthreads();
        rbase[tid] += u;
        __syncthreads();
    }
    rbase[tid] -= v;     // exclusive
    __syncthreads();
}

// atomic-free scatter: slot = rbase[row] + off[bin] + rank
__global__ __launch_bounds__(256) void k_scat(const float4* __restrict__ st,
                                              const unsigned* __restrict__ meta,
                                              const unsigned* __restrict__ off,
                                              Rec* __restrict__ rec) {
#pragma clang fp contract(off)
    __shared__ unsigned rbase[256];
    __shared__ unsigned rtot[256];
    int b   = blockIdx.x & 7;
    int sub = blockIdx.x >> 3;
    load_rowbases(b, rbase, rtot);

    int p0 = (b << 16) + sub * 512 + threadIdx.x;
    #pragma unroll
    for (int q = 0; q < 2; ++q) {
        int idx = p0 + q * 256;
        float4 s = st[idx];
        unsigned m = meta[idx];
        unsigned bin = m >> 16, rank = m & 0xFFFFu;
        unsigned row = bin >> 8;
        unsigned slot = rbase[row] + off[(b << 16) + bin] + rank;
        Rec r;
        r.sx = fmul_sr(s.x, 255.0f);   // same bits as adv_core's sx
        r.sy = fmul_sr(s.y, 255.0f);
        r.nR = s.z;
        rec[((size_t)b << 16) + slot] = r;
    }
}

// per-tile gather (32x16 cells) + fused advection of step t+1
__global__ __launch_bounds__(256) void k_gathadv(
        const Rec* __restrict__ rec, const unsigned* __restrict__ off,
        float* __restrict__ out, const float* __restrict__ dec,
        float4* __restrict__ st, unsigned* __restrict__ hist,
        unsigned* __restrict__ meta, int t) {
#pragma clang fp contract(off)
    __shared__ unsigned rbase[256];
    __shared__ unsigned rtot[256];
    __shared__ float a_lds[16][32];
    __shared__ float w_lds[16][32];

    int b    = blockIdx.x & 7;
    int tile = blockIdx.x >> 3;          // 0..127
    int x0 = (tile & 7) * 32;
    int y0 = (tile >> 3) * 16;
    int tid = threadIdx.x;

    load_rowbases(b, rbase, rtot);

    a_lds[tid >> 5][tid & 31] = 0.0f;
    w_lds[tid >> 5][tid & 31] = 0.0f;
    a_lds[(tid >> 5) + 8][tid & 31] = 0.0f;
    w_lds[(tid >> 5) + 8][tid & 31] = 0.0f;
    __syncthreads();

    const unsigned* ob = off + (b << 16);
    const Rec*      rb = rec + ((size_t)b << 16);
    int wave = tid >> 6, lane = tid & 63;

    for (int r = wave; r < 17; r += 4) {
        int by = y0 - 1 + r;
        if (by < 0) continue;            // by <= 255 always
        int bx0 = (x0 == 0) ? 0 : x0 - 1;
        int bx1 = x0 + 31;               // <= 255
        unsigned base = rbase[by];
        unsigned sbeg = base + ob[by * 256 + bx0];
        unsigned send = base + ((bx1 == 255) ? rtot[by] : ob[by * 256 + bx1 + 1]);
        for (unsigned i = sbeg + lane; i < send; i += 64) {
            Rec rr = rb[i];
            float sx0f = floorf(rr.sx), sy0f = floorf(rr.sy);
            #pragma unroll
            for (int k = 0; k < 4; ++k) {
                float dxf = (float)(k & 1), dyf = (float)(k >> 1);
                float xc = sx0f + dxf, yc = sy0f + dyf;   // exact
                int cxi = (int)xc, cy = (int)yc;
                if (cxi >= x0 && cxi < x0 + 32 && cy >= y0 && cy < y0 + 16) {
                    float w = fmul_sr(1.0f - fabsf(rr.sx - xc),
                                      1.0f - fabsf(rr.sy - yc));
                    if (w != 0.0f) {                      // matches splat skip
                        atomicAdd(&a_lds[cy - y0][cxi - x0], fmul_sr(rr.nR, w));
                        atomicAdd(&w_lds[cy - y0][cxi - x0], w);
                    }
                }
            }
        }
    }
    __syncthreads();

    size_t obase = (size_t)(b * TT + t) * HW;
    #pragma unroll
    for (int q = 0; q < 2; ++q) {
        int c = tid + q * 256;
        int row = c >> 5, col = c & 31;
        float a = a_lds[row][col];
        float w = w_lds[row][col];
        out[obase + (size_t)(y0 + row) * 256 + x0 + col] =
            (w == 0.0f) ? EMPTY_FLOOR : a / fmaxf(w, 1e-8f);
    }

    // ---- fused advection of step t+1 ----
    int tA = t + 1;
    if (tA < TT) {
        int sub = blockIdx.x >> 3;
        int p0  = (b << 16) + sub * 512 + tid;
        #pragma unroll
        for (int q = 0; q < 2; ++q) {
            int idx = p0 + q * 256;
            float4 s = st[idx];
            adv_core(dec, s, hist, meta, idx, b, tA);
            st[idx] = s;
        }
    }
}

extern "C" void kernel_launch(void* const* d_in, const int* in_sizes, int n_in,
                              void* d_out, int out_size, void* d_ws, size_t ws_size,
                              hipStream_t stream) {
    const float* x   = (const float*)d_in[0];
    const float* dec = (const float*)d_in[1];
    float* out = (float*)d_out;

    float4*   st   = (float4*)d_ws;                                       // 8 MB
    Rec*      rec  = (Rec*)(st + (size_t)NPT);                            // 6 MB
    unsigned* hist = (unsigned*)((char*)rec + (size_t)NPT * sizeof(Rec)); // 2 MB
    unsigned* off  = hist + (size_t)NPT;                                  // 2 MB
    unsigned* meta = off + (size_t)NPT;                                   // 2 MB = 20 MB

    hipMemsetAsync(hist, 0, (size_t)NPT * sizeof(unsigned), stream);
    k_initadv<<<1024, 256, 0, stream>>>(x, dec, st, hist, meta);
    for (int t = 0; t < TT; ++t) {
        k_scan<<<2048, 256, 0, stream>>>(hist, off);
        k_scat<<<1024, 256, 0, stream>>>(st, meta, off, rec);
        k_gathadv<<<1024, 256, 0, stream>>>(rec, off, out, dec, st, hist, meta, t);
    }
}

// Round 24
// 700.399 us; speedup vs baseline: 4.6676x; 1.0146x over previous
//
#include <hip/hip_runtime.h>

#define BB 8
#define TT 16
#define HH 256
#define WW 256
#define HW (HH*WW)            // 65536
#define NPT (BB*HW)           // 524288 points
#define EMPTY_FLOOR 0.012f

// ws (20 MB, proven): st float4[NPT]=8MB | rec Rec[NPT]=6MB | hist u32[NPT]=2MB
//                     | off u32[NPT]=2MB | meta u32[NPT]=2MB
// Arithmetic VERBATIM R15 (A-init f32 bits; f64 step math, f32 state rounding;
// R6-f32 defused splat weights; empty-cell floor 0.012). DO NOT TOUCH.
// R24 = R23 + (a) advection split into issue-early texel loads / late f64
// reduce inside k_gathadv (latency hidden under gather stream); (b) wave-
// shuffle scans (1-2 barriers instead of 16) in k_scan / load_rowbases.

struct Rec { float sx, sy, nR; };

__device__ unsigned g_rowtot[BB][HH];   // visibility via kernel boundary

__device__ __forceinline__ float fmul_sr(float a, float b) {
    float r = a * b;
    __asm__("" : "+v"(r));
    return r;
}

// ---------- advection split: pre (loads) / post (f64 reduce) ----------
struct AdvPre {
    double ix, iy;
    float tU[4], tV[4], tC[4];
    float X, Y, R;
};

__device__ __forceinline__ void adv_pre(const float* __restrict__ dec,
                                        const float4 s, AdvPre& a,
                                        int b, int t) {
    const float* U = dec + (size_t)((b * TT + t) * 3) * HW;
    const float* V = U + HW;
    const float* C = U + 2 * HW;
    a.X = s.x; a.Y = s.y; a.R = s.z;
    double X = (double)s.x, Y = (double)s.y;
    a.ix = X * 256.0 - 0.5;
    a.iy = Y * 256.0 - 0.5;
    double x0 = floor(a.ix), y0 = floor(a.iy);
    #pragma unroll
    for (int k = 0; k < 4; ++k) {
        double xc = x0 + (double)(k & 1), yc = y0 + (double)(k >> 1);
        int xi = (int)fmin(fmax(xc, 0.0), 255.0);
        int yi = (int)fmin(fmax(yc, 0.0), 255.0);
        int ii = yi * WW + xi;
        a.tU[k] = U[ii];
        a.tV[k] = V[ii];
        a.tC[k] = C[ii];
    }
}

__device__ __forceinline__ void adv_post(const AdvPre& a, float4& s,
                                         unsigned* __restrict__ hist,
                                         unsigned* __restrict__ meta,
                                         int idx, int b) {
    double ix = a.ix, iy = a.iy;
    double x0 = floor(ix), y0 = floor(iy);
    double gU = 0.0, gV = 0.0, gC = 0.0;
    #pragma unroll
    for (int k = 0; k < 4; ++k) {
        double dxf = (double)(k & 1), dyf = (double)(k >> 1);
        double xc = x0 + dxf, yc = y0 + dyf;
        double w = (1.0 - fabs(ix - xc)) * (1.0 - fabs(iy - yc));
        bool valid = (xc >= 0.0) && (xc < 256.0) && (yc >= 0.0) && (yc < 256.0);
        double wv = valid ? w : 0.0;
        double uT = (((double)a.tU[k] - 0.5) * 5.0) / 256.0;
        double vT = (((double)a.tV[k] - 0.5) * 5.0) / 256.0;
        double cT = (double)a.tC[k];
        gU = gU + uT * wv;
        gV = gV + vT * wv;
        gC = gC + cT * wv;
    }
    double nXd = (double)a.X + gU; nXd = fmin(fmax(nXd, 0.0), 1.0);
    double nYd = (double)a.Y + gV; nYd = fmin(fmax(nYd, 0.0), 1.0);
    double nRd = (double)a.R * gC; nRd = fmin(fmax(nRd, 0.0), 1.0);
    float nX = (float)nXd;
    float nY = (float)nYd;
    float nR = (float)nRd;
    s.x = nX; s.y = nY; s.z = nR; s.w = 0.0f;

    float sx = fmul_sr(nX, 255.0f);
    float sy = fmul_sr(nY, 255.0f);
    int bin = ((int)floorf(sy)) * 256 + (int)floorf(sx);   // 0..65535
    unsigned rank = atomicAdd(&hist[(b << 16) + bin], 1u); // rank < 65536
    meta[idx] = ((unsigned)bin << 16) | rank;
}

// init state + advection of step 0 (hist pre-zeroed by memsetAsync)
__global__ __launch_bounds__(256) void k_initadv(
        const float* __restrict__ x, const float* __restrict__ dec,
        float4* __restrict__ st, unsigned* __restrict__ hist,
        unsigned* __restrict__ meta) {
#pragma clang fp contract(off)
    int b   = blockIdx.x & 7;
    int sub = blockIdx.x >> 3;
    int p0  = (b << 16) + sub * 512 + threadIdx.x;
    #pragma unroll
    for (int q = 0; q < 2; ++q) {
        int idx = p0 + q * 256;
        int p  = idx & (HW - 1);
        int px = p & (WW - 1);
        int py = p >> 8;
        float4 s;
        s.x = (float)px * (1.0f / 255.0f);   // A-init bits (proven basin)
        s.y = (float)py * (1.0f / 255.0f);
        s.z = x[(size_t)(b * TT + (TT - 1)) * HW + p];
        s.w = 0.0f;
        AdvPre a;
        adv_pre(dec, s, a, b, 0);
        adv_post(a, s, hist, meta, idx, b);
        st[idx] = s;
    }
}

// 2048 blocks (batch=blockIdx&7, row=blockIdx>>3): wave-shuffle row scan.
__global__ __launch_bounds__(256) void k_scan(unsigned* __restrict__ hist,
                                              unsigned* __restrict__ off) {
    int b    = blockIdx.x & 7;
    int row  = blockIdx.x >> 3;
    int tid  = threadIdx.x;
    int lane = tid & 63, wave = tid >> 6;
    int bin  = (b << 16) + row * 256 + tid;

    unsigned v = hist[bin];
    unsigned sc = v;                         // inclusive wave scan
    #pragma unroll
    for (int d = 1; d < 64; d <<= 1) {
        unsigned u = (unsigned)__shfl_up((int)sc, d);
        if (lane >= d) sc += u;
    }
    __shared__ unsigned wsum[4];
    if (lane == 63) wsum[wave] = sc;
    __syncthreads();
    unsigned base = 0;
    #pragma unroll
    for (int w = 0; w < 4; ++w) if (w < wave) base += wsum[w];
    unsigned incl = base + sc;
    off[bin]  = incl - v;
    hist[bin] = 0u;
    if (tid == 255) g_rowtot[b][row] = incl;
}

// wave-shuffle exclusive row-base scan of g_rowtot[b][*]
__device__ __forceinline__ void load_rowbases(int b, unsigned* rbase,
                                              unsigned* rtot) {
    __shared__ unsigned wsum[4];
    int tid  = threadIdx.x;
    int lane = tid & 63, wave = tid >> 6;
    unsigned v = g_rowtot[b][tid];
    rtot[tid] = v;
    unsigned sc = v;
    #pragma unroll
    for (int d = 1; d < 64; d <<= 1) {
        unsigned u = (unsigned)__shfl_up((int)sc, d);
        if (lane >= d) sc += u;
    }
    if (lane == 63) wsum[wave] = sc;
    __syncthreads();
    unsigned base = 0;
    #pragma unroll
    for (int w = 0; w < 4; ++w) if (w < wave) base += wsum[w];
    rbase[tid] = base + sc - v;              // exclusive
    __syncthreads();
}

// atomic-free scatter: slot = rbase[row] + off[bin] + rank
__global__ __launch_bounds__(256) void k_scat(const float4* __restrict__ st,
                                              const unsigned* __restrict__ meta,
                                              const unsigned* __restrict__ off,
                                              Rec* __restrict__ rec) {
#pragma clang fp contract(off)
    __shared__ unsigned rbase[256];
    __shared__ unsigned rtot[256];
    int b   = blockIdx.x & 7;
    int sub = blockIdx.x >> 3;
    load_rowbases(b, rbase, rtot);

    int p0 = (b << 16) + sub * 512 + threadIdx.x;
    #pragma unroll
    for (int q = 0; q < 2; ++q) {
        int idx = p0 + q * 256;
        float4 s = st[idx];
        unsigned m = meta[idx];
        unsigned bin = m >> 16, rank = m & 0xFFFFu;
        unsigned row = bin >> 8;
        unsigned slot = rbase[row] + off[(b << 16) + bin] + rank;
        Rec r;
        r.sx = fmul_sr(s.x, 255.0f);   // same bits as adv_post's sx
        r.sy = fmul_sr(s.y, 255.0f);
        r.nR = s.z;
        rec[((size_t)b << 16) + slot] = r;
    }
}

// per-tile gather (32x16) + advection t+1 with issue-early texel loads
__global__ __launch_bounds__(256) void k_gathadv(
        const Rec* __restrict__ rec, const unsigned* __restrict__ off,
        float* __restrict__ out, const float* __restrict__ dec,
        float4* __restrict__ st, unsigned* __restrict__ hist,
        unsigned* __restrict__ meta, int t) {
#pragma clang fp contract(off)
    __shared__ unsigned rbase[256];
    __shared__ unsigned rtot[256];
    __shared__ float a_lds[16][32];
    __shared__ float w_lds[16][32];

    int b    = blockIdx.x & 7;
    int tile = blockIdx.x >> 3;          // 0..127
    int x0 = (tile & 7) * 32;
    int y0 = (tile >> 3) * 16;
    int tid = threadIdx.x;

    // ---- issue advection loads EARLY (consumed after gather) ----
    int tA = t + 1;
    int sub = blockIdx.x >> 3;
    int pA  = (b << 16) + sub * 512 + tid;
    float4 s0, s1;
    AdvPre ap0, ap1;
    if (tA < TT) {
        s0 = st[pA];
        s1 = st[pA + 256];
        adv_pre(dec, s0, ap0, b, tA);
        adv_pre(dec, s1, ap1, b, tA);
    }

    load_rowbases(b, rbase, rtot);

    a_lds[tid >> 5][tid & 31] = 0.0f;
    w_lds[tid >> 5][tid & 31] = 0.0f;
    a_lds[(tid >> 5) + 8][tid & 31] = 0.0f;
    w_lds[(tid >> 5) + 8][tid & 31] = 0.0f;
    __syncthreads();

    const unsigned* ob = off + (b << 16);
    const Rec*      rb = rec + ((size_t)b << 16);
    int wave = tid >> 6, lane = tid & 63;

    for (int r = wave; r < 17; r += 4) {
        int by = y0 - 1 + r;
        if (by < 0) continue;            // by <= 255 always
        int bx0 = (x0 == 0) ? 0 : x0 - 1;
        int bx1 = x0 + 31;               // <= 255
        unsigned base = rbase[by];
        unsigned sbeg = base + ob[by * 256 + bx0];
        unsigned send = base + ((bx1 == 255) ? rtot[by] : ob[by * 256 + bx1 + 1]);
        for (unsigned i = sbeg + lane; i < send; i += 64) {
            Rec rr = rb[i];
            float sx0f = floorf(rr.sx), sy0f = floorf(rr.sy);
            #pragma unroll
            for (int k = 0; k < 4; ++k) {
                float dxf = (float)(k & 1), dyf = (float)(k >> 1);
                float xc = sx0f + dxf, yc = sy0f + dyf;   // exact
                int cxi = (int)xc, cy = (int)yc;
                if (cxi >= x0 && cxi < x0 + 32 && cy >= y0 && cy < y0 + 16) {
                    float w = fmul_sr(1.0f - fabsf(rr.sx - xc),
                                      1.0f - fabsf(rr.sy - yc));
                    if (w != 0.0f) {                      // matches splat skip
                        atomicAdd(&a_lds[cy - y0][cxi - x0], fmul_sr(rr.nR, w));
                        atomicAdd(&w_lds[cy - y0][cxi - x0], w);
                    }
                }
            }
        }
    }
    __syncthreads();

    size_t obase = (size_t)(b * TT + t) * HW;
    #pragma unroll
    for (int q = 0; q < 2; ++q) {
        int c = tid + q * 256;
        int row = c >> 5, col = c & 31;
        float a = a_lds[row][col];
        float w = w_lds[row][col];
        out[obase + (size_t)(y0 + row) * 256 + x0 + col] =
            (w == 0.0f) ? EMPTY_FLOOR : a / fmaxf(w, 1e-8f);
    }

    // ---- finish advection of step t+1 ----
    if (tA < TT) {
        adv_post(ap0, s0, hist, meta, pA, b);
        st[pA] = s0;
        adv_post(ap1, s1, hist, meta, pA + 256, b);
        st[pA + 256] = s1;
    }
}

extern "C" void kernel_launch(void* const* d_in, const int* in_sizes, int n_in,
                              void* d_out, int out_size, void* d_ws, size_t ws_size,
                              hipStream_t stream) {
    const float* x   = (const float*)d_in[0];
    const float* dec = (const float*)d_in[1];
    float* out = (float*)d_out;

    float4*   st   = (float4*)d_ws;                                       // 8 MB
    Rec*      rec  = (Rec*)(st + (size_t)NPT);                            // 6 MB
    unsigned* hist = (unsigned*)((char*)rec + (size_t)NPT * sizeof(Rec)); // 2 MB
    unsigned* off  = hist + (size_t)NPT;                                  // 2 MB
    unsigned* meta = off + (size_t)NPT;                                   // 2 MB = 20 MB

    hipMemsetAsync(hist, 0, (size_t)NPT * sizeof(unsigned), stream);
    k_initadv<<<1024, 256, 0, stream>>>(x, dec, st, hist, meta);
    for (int t = 0; t < TT; ++t) {
        k_scan<<<2048, 256, 0, stream>>>(hist, off);
        k_scat<<<1024, 256, 0, stream>>>(st, meta, off, rec);
        k_gathadv<<<1024, 256, 0, stream>>>(rec, off, out, dec, st, hist, meta, t);
    }
}